// Round 11
// baseline (133.409 us; speedup 1.0000x reference)
//
#include <hip/hip_runtime.h>
#include <hip/hip_bf16.h>
#include <stdint.h>

#define NODES 50000
#define EDGES 800000
#define CAP   64        // per-node bucket capacity (deg ~ Poisson(16))
#define GRP   6250      // nodes per XCD group (8 groups)
#define BINCAP 131072   // per-bin capacity (expected ~100k +- 0.3k)

typedef __attribute__((ext_vector_type(8))) short bf16x8;
typedef __attribute__((ext_vector_type(8))) unsigned short u16x8;
typedef __attribute__((ext_vector_type(4))) unsigned short u16x4;
typedef __attribute__((ext_vector_type(4))) float f32x4;
typedef unsigned short ushort_t;

__device__ __forceinline__ ushort_t f2bf(float f) {   // RNE f32->bf16 bits
    unsigned u = __float_as_uint(f);
    unsigned r = (u + 0x7fff + ((u >> 16) & 1)) >> 16;
    return (ushort_t)r;
}
__device__ __forceinline__ float bf2f(ushort_t h) {
    return __uint_as_float(((unsigned)h) << 16);
}

// ---------------- prepA: radix partition + cvt_x + weight packs ----------------
// blocks [0,391):      LDS-staged 8-way partition of edges by dst range.
//                      One streaming pass (6.4 MB), packed u32 bins out
//                      (coalesced chunk writes, 1 global atomicAdd per flush).
// blocks [391,6641):   x -> bf16 into xbf (NT load x; normal store xbf)
// blocks [6641,6657):  pack w1 into MFMA fragment order
// blocks [6657,6662):  pack w2 likewise
__global__ __launch_bounds__(256) void prepA(
    const float* __restrict__ x, const int* __restrict__ src,
    const int* __restrict__ dst,
    const float* __restrict__ Wr1, const float* __restrict__ Wl1,
    const float* __restrict__ Wr2, const float* __restrict__ Wl2,
    unsigned* __restrict__ bins, unsigned* __restrict__ bin_cnt,
    ushort_t* __restrict__ xbf, ushort_t* __restrict__ w1p,
    ushort_t* __restrict__ w2p) {
    int b = blockIdx.x;
    if (b < 391) {
        __shared__ int lcnt[8];
        __shared__ unsigned lbase[8];
        __shared__ unsigned lbin[8][1024];
        int t = threadIdx.x;
        for (int tile = 0; tile < 2; ++tile) {
            if (t < 8) lcnt[t] = 0;
            __syncthreads();
            int e0 = (b * 2 + tile) * 1024;
#pragma unroll
            for (int k = 0; k < 4; ++k) {
                int e = e0 + k * 256 + t;
                if (e < EDGES) {
                    int d = dst[e], s = src[e];
                    int g = d / GRP;
                    int slot = atomicAdd(&lcnt[g], 1);
                    lbin[g][slot] = ((unsigned)(d - g * GRP) << 16) | (unsigned)s;
                }
            }
            __syncthreads();
            if (t < 8) lbase[t] = atomicAdd(&bin_cnt[t], (unsigned)lcnt[t]);
            __syncthreads();
            for (int g = 0; g < 8; ++g) {
                int cnt = lcnt[g];
                unsigned base = lbase[g];
                for (int i = t; i < cnt; i += 256) {
                    unsigned idx = base + i;
                    if (idx < BINCAP)
                        bins[(size_t)g * BINCAP + idx] = lbin[g][i];
                }
            }
            __syncthreads();
        }
    } else if (b < 6641) {                // 6250*256 == NODES*32 exactly
        int idx = (b - 391) * 256 + threadIdx.x;
        int i = idx >> 5, c = idx & 31;
        f32x4 v = __builtin_nontemporal_load(
            reinterpret_cast<const f32x4*>(x + (size_t)i * 128 + c * 4));
        u16x4 h;
        h[0] = f2bf(v[0]); h[1] = f2bf(v[1]); h[2] = f2bf(v[2]); h[3] = f2bf(v[3]);
        *reinterpret_cast<u16x4*>(xbf + (size_t)i * 128 + c * 4) = h;
    } else if (b < 6657) {                // 4096 threads: w1 fragment pack
        int t = (b - 6641) * 256 + threadIdx.x;     // t = (nf*8+kc)*64+lane
        int nf = t >> 9, kc = (t >> 6) & 7, lane = t & 63;
        int r = nf * 16 + (lane & 15);
        int k2 = kc * 32 + ((lane >> 4) << 3);
        u16x8 o;
#pragma unroll
        for (int j = 0; j < 8; ++j) {
            int kk = k2 + j;
            float v = (kk < 128) ? Wr1[r * 128 + kk] : Wl1[r * 128 + (kk - 128)];
            o[j] = f2bf(v);
        }
        *reinterpret_cast<u16x8*>(w1p + (size_t)t * 8) = o;
    } else {                              // 1280 threads: w2 fragment pack
        int t = (b - 6657) * 256 + threadIdx.x;     // t = (nf*4+kc)*64+lane
        if (t >= 1280) return;
        int nf = t >> 8, kc = (t >> 6) & 3, lane = t & 63;
        int r = nf * 16 + (lane & 15);
        int k2 = kc * 32 + ((lane >> 4) << 3);
        u16x8 o;
#pragma unroll
        for (int j = 0; j < 8; ++j) {
            int kk = k2 + j;
            float v = (r < 40) ? Wr2[r * 128 + kk] : Wl2[(r - 40) * 128 + kk];
            o[j] = f2bf(v);
        }
        *reinterpret_cast<u16x8*>(w2p + (size_t)t * 8) = o;
    }
}

// ---------------- prepB: XCD-local bucket fill from bins ----------------
// Group g = blockIdx&7 drains bin g: ~400 KB sequential read; random writes
// confined to g's 800 KB esrc slice + deg -- L2-resident, written back once.
__global__ __launch_bounds__(256) void prepB(
    const unsigned* __restrict__ bins, const unsigned* __restrict__ bin_cnt,
    int* __restrict__ deg, ushort_t* __restrict__ esrc) {
    int g = blockIdx.x & 7, chunk = blockIdx.x >> 3;   // 49 chunks per group
    unsigned cnt = bin_cnt[g];
    if (cnt > BINCAP) cnt = BINCAP;
    const unsigned* bp = bins + (size_t)g * BINCAP;
    int base = g * GRP;
    for (unsigned i = chunk * 256 + threadIdx.x; i < cnt; i += 49 * 256) {
        unsigned pk = bp[i];
        int d = base + (int)(pk >> 16);
        int s = (int)(pk & 0xffffu);
        int p = atomicAdd(&deg[d], 1);
        if (p < CAP) esrc[(size_t)d * CAP + p] = (ushort_t)s;
    }
}

// ---------------- layer-1 gather-mean (bf16), MLP-unrolled ----------------
// 16 lanes/node, ushort8 (16B) per lane; 4 neighbors in flight, 2 acc chains.
__global__ __launch_bounds__(256) void aggx(
    const ushort_t* __restrict__ xbf, ushort_t* __restrict__ mbf,
    const ushort_t* __restrict__ esrc, const int* __restrict__ deg) {
    int idx = blockIdx.x * 256 + threadIdx.x;
    int i = idx >> 4, c = idx & 15;
    if (i >= NODES) return;
    int dg = deg[i];
    int n = dg < CAP ? dg : CAP;
    const ushort_t* ep = esrc + (size_t)i * CAP;
    float a0[8] = {}, a1[8] = {};
    int j = 0;
    for (; j + 4 <= n; j += 4) {
        int s0 = ep[j], s1 = ep[j + 1], s2 = ep[j + 2], s3 = ep[j + 3];
        u16x8 v0 = *reinterpret_cast<const u16x8*>(xbf + (size_t)s0 * 128 + c * 8);
        u16x8 v1 = *reinterpret_cast<const u16x8*>(xbf + (size_t)s1 * 128 + c * 8);
        u16x8 v2 = *reinterpret_cast<const u16x8*>(xbf + (size_t)s2 * 128 + c * 8);
        u16x8 v3 = *reinterpret_cast<const u16x8*>(xbf + (size_t)s3 * 128 + c * 8);
#pragma unroll
        for (int k = 0; k < 8; ++k) {
            a0[k] += bf2f(v0[k]) + bf2f(v2[k]);
            a1[k] += bf2f(v1[k]) + bf2f(v3[k]);
        }
    }
    for (; j < n; ++j) {
        int s = ep[j];
        u16x8 v = *reinterpret_cast<const u16x8*>(xbf + (size_t)s * 128 + c * 8);
#pragma unroll
        for (int k = 0; k < 8; ++k) a0[k] += bf2f(v[k]);
    }
    float ci = 1.0f / fmaxf((float)dg, 1.0f);
    u16x8 m;
#pragma unroll
    for (int k = 0; k < 8; ++k) m[k] = f2bf((a0[k] + a1[k]) * ci);
    *reinterpret_cast<u16x8*>(mbf + (size_t)i * 128 + c * 8) = m;
}

// ---------------- fused GEMM1 + GEMM2 (packed weights, split A) ----------------
__global__ __launch_bounds__(256) void gemm12(
    const ushort_t* __restrict__ xbf, const ushort_t* __restrict__ mbf,
    const ushort_t* __restrict__ w1p, const ushort_t* __restrict__ w2p,
    const float* __restrict__ b1, float* __restrict__ emb,
    ushort_t* __restrict__ V, int M) {
    __shared__ ushort_t hs[64][136];      // stride 136: 16B-aligned rows
    const int wave = threadIdx.x >> 6, lane = threadIdx.x & 63;
    const int r0 = blockIdx.x * 64 + wave * 16;
    int arow = r0 + (lane & 15); if (arow >= M) arow = M - 1;
    const int klane = (lane >> 4) * 8;

    f32x4 acc[8] = {};
#pragma unroll
    for (int kc = 0; kc < 8; ++kc) {
        const ushort_t* abase = (kc < 4) ? xbf : mbf;
        bf16x8 a = *reinterpret_cast<const bf16x8*>(
            abase + (size_t)arow * 128 + (kc & 3) * 32 + klane);
        bf16x8 wv[8];
#pragma unroll
        for (int nf = 0; nf < 8; ++nf)
            wv[nf] = *reinterpret_cast<const bf16x8*>(
                w1p + (size_t)((nf * 8 + kc) * 64 + lane) * 8);
#pragma unroll
        for (int nf = 0; nf < 8; ++nf)
            acc[nf] = __builtin_amdgcn_mfma_f32_16x16x32_bf16(a, wv[nf], acc[nf], 0, 0, 0);
    }

    const int crow0r = wave * 16 + (lane >> 4) * 4;     // row within tile
    const int crow0  = blockIdx.x * 64 + crow0r;
    const int ccol   = lane & 15;
#pragma unroll
    for (int nf = 0; nf < 8; ++nf) {
        int col = nf * 16 + ccol;
        float bv = b1[col];
#pragma unroll
        for (int r = 0; r < 4; ++r) {
            int row = crow0 + r;
            float val = acc[nf][r] + bv;
            if (row < M)
                __builtin_nontemporal_store(val, emb + (size_t)row * 128 + col);
            hs[crow0r + r][col] = f2bf(fmaxf(val, 0.f));
        }
    }
    __syncthreads();

    f32x4 acc2[5] = {};
#pragma unroll
    for (int kc = 0; kc < 4; ++kc) {
        bf16x8 a = *reinterpret_cast<const bf16x8*>(
            &hs[wave * 16 + (lane & 15)][kc * 32 + klane]);
        bf16x8 wv[5];
#pragma unroll
        for (int nf = 0; nf < 5; ++nf)
            wv[nf] = *reinterpret_cast<const bf16x8*>(
                w2p + (size_t)((nf * 4 + kc) * 64 + lane) * 8);
#pragma unroll
        for (int nf = 0; nf < 5; ++nf)
            acc2[nf] = __builtin_amdgcn_mfma_f32_16x16x32_bf16(a, wv[nf], acc2[nf], 0, 0, 0);
    }
#pragma unroll
    for (int nf = 0; nf < 5; ++nf) {
        int col = nf * 16 + ccol;
#pragma unroll
        for (int r = 0; r < 4; ++r) {
            int row = crow0 + r;
            if (row < M) V[(size_t)row * 80 + col] = f2bf(acc2[nf][r]);
        }
    }
}

// ---------------- layer-2 gather-mean + epilogue (bf16 V), MLP-unrolled ----------------
__global__ __launch_bounds__(256) void agg2(
    const ushort_t* __restrict__ V, const ushort_t* __restrict__ esrc,
    const int* __restrict__ deg, const float* __restrict__ b2,
    float* __restrict__ logits) {
    int idx = blockIdx.x * 256 + threadIdx.x;
    int i = idx >> 3, c = idx & 7;
    if (i >= NODES || c >= 5) return;
    int dg = deg[i];
    int n = dg < CAP ? dg : CAP;
    const ushort_t* ep = esrc + (size_t)i * CAP;
    float a0[8] = {}, a1[8] = {};
    int j = 0;
    for (; j + 4 <= n; j += 4) {
        int s0 = ep[j], s1 = ep[j + 1], s2 = ep[j + 2], s3 = ep[j + 3];
        u16x8 v0 = *reinterpret_cast<const u16x8*>(V + (size_t)s0 * 80 + 40 + c * 8);
        u16x8 v1 = *reinterpret_cast<const u16x8*>(V + (size_t)s1 * 80 + 40 + c * 8);
        u16x8 v2 = *reinterpret_cast<const u16x8*>(V + (size_t)s2 * 80 + 40 + c * 8);
        u16x8 v3 = *reinterpret_cast<const u16x8*>(V + (size_t)s3 * 80 + 40 + c * 8);
#pragma unroll
        for (int k = 0; k < 8; ++k) {
            a0[k] += bf2f(v0[k]) + bf2f(v2[k]);
            a1[k] += bf2f(v1[k]) + bf2f(v3[k]);
        }
    }
    for (; j < n; ++j) {
        int s = ep[j];
        u16x8 v = *reinterpret_cast<const u16x8*>(V + (size_t)s * 80 + 40 + c * 8);
#pragma unroll
        for (int k = 0; k < 8; ++k) a0[k] += bf2f(v[k]);
    }
    float ci = 1.0f / fmaxf((float)dg, 1.0f);
    u16x8 sv = *reinterpret_cast<const u16x8*>(V + (size_t)i * 80 + c * 8);
    float o[8];
#pragma unroll
    for (int k = 0; k < 8; ++k)
        o[k] = bf2f(sv[k]) + (a0[k] + a1[k]) * ci + b2[c * 8 + k];
    float4* dst4 = reinterpret_cast<float4*>(logits + (size_t)i * 40 + c * 8);
    dst4[0] = make_float4(o[0], o[1], o[2], o[3]);
    dst4[1] = make_float4(o[4], o[5], o[6], o[7]);
}

extern "C" void kernel_launch(void* const* d_in, const int* in_sizes, int n_in,
                              void* d_out, int out_size, void* d_ws, size_t ws_size,
                              hipStream_t stream) {
    const float* x   = (const float*)d_in[0];
    const int*   ei  = (const int*)d_in[1];
    const float* Wl1 = (const float*)d_in[2];
    const float* Wr1 = (const float*)d_in[3];
    const float* b1  = (const float*)d_in[4];
    const float* Wl2 = (const float*)d_in[5];
    const float* Wr2 = (const float*)d_in[6];
    const float* b2  = (const float*)d_in[7];
    const int* src = ei;              // edge_index[0]
    const int* dst = ei + EDGES;      // edge_index[1]

    // Workspace (~44.5 MB):
    //   [0, 12.8M)          xbf [50000x128 bf16]
    //   [12.8M, 25.6M)      mbf [50000x128 bf16]
    //   [25.6M, 33.6M)      V   [50000x80 bf16]
    //   [33.6M, 40.0M)      esrc [50000*64 ushort]
    //   [40.0M, 40.2M)      deg [50000 int] + bin_cnt [8 u32] (one memset)
    //   [40.200064M, ...)   w1p, w2p (packed bf16)
    //   [40.28608M, 44.5M)  bins [8 x 131072 u32]
    char* ws = (char*)d_ws;
    ushort_t* xbf     = (ushort_t*)ws;
    ushort_t* mbf     = (ushort_t*)(ws + 12800000);
    ushort_t* V       = (ushort_t*)(ws + 25600000);
    ushort_t* esrc    = (ushort_t*)(ws + 33600000);
    int*      deg     = (int*)(ws + 40000000);
    unsigned* bin_cnt = (unsigned*)(ws + 40200000);
    ushort_t* w1p     = (ushort_t*)(ws + 40200064);
    ushort_t* w2p     = (ushort_t*)(ws + 40265600);
    unsigned* bins    = (unsigned*)(ws + 40286080);

    float* logits_out = (float*)d_out;                   // 50000*40 f32
    float* emb_out    = logits_out + (size_t)NODES * 40; // 50000*128 f32

    hipMemsetAsync(deg, 0, 200064, stream);   // deg + bin_cnt

    prepA<<<6662, 256, 0, stream>>>(x, src, dst, Wr1, Wl1, Wr2, Wl2,
                                    bins, bin_cnt, xbf, w1p, w2p);

    prepB<<<392, 256, 0, stream>>>(bins, bin_cnt, deg, esrc);

    aggx<<<3125, 256, 0, stream>>>(xbf, mbf, esrc, deg);

    gemm12<<<(NODES + 63) / 64, 256, 0, stream>>>(xbf, mbf, w1p, w2p, b1,
                                                  emb_out, V, NODES);

    agg2<<<(NODES * 8 + 255) / 256, 256, 0, stream>>>(V, esrc, deg, b2, logits_out);
}

// Round 12
// 133.335 us; speedup vs baseline: 1.0006x; 1.0006x over previous
//
#include <hip/hip_runtime.h>
#include <hip/hip_bf16.h>
#include <stdint.h>

#define NODES 50000
#define EDGES 800000
#define CAP   64        // per-node bucket capacity (deg ~ Poisson(16))
#define GRP   6250      // nodes per XCD group (8 groups)
#define BINCAP 131072   // per-bin capacity (expected ~100k +- 0.3k)

typedef __attribute__((ext_vector_type(8))) short bf16x8;
typedef __attribute__((ext_vector_type(8))) unsigned short u16x8;
typedef __attribute__((ext_vector_type(4))) unsigned short u16x4;
typedef __attribute__((ext_vector_type(4))) float f32x4;
typedef unsigned short ushort_t;

__device__ __forceinline__ ushort_t f2bf(float f) {   // RNE f32->bf16 bits
    unsigned u = __float_as_uint(f);
    unsigned r = (u + 0x7fff + ((u >> 16) & 1)) >> 16;
    return (ushort_t)r;
}
__device__ __forceinline__ float bf2f(ushort_t h) {
    return __uint_as_float(((unsigned)h) << 16);
}

// ---------------- zero deg + bin_cnt (replaces pathological rocclr fill) ----------------
__global__ __launch_bounds__(256) void zerok(int* __restrict__ deg,
                                             unsigned* __restrict__ bin_cnt) {
    int t = blockIdx.x * 256 + threadIdx.x;
    if (t < 25000) reinterpret_cast<int2*>(deg)[t] = make_int2(0, 0);
    else if (t < 25008) bin_cnt[t - 25000] = 0u;
}

// ---------------- prepA: radix partition + cvt_x + weight packs ----------------
// blocks [0,391):      LDS-staged 8-way partition of edges by dst range.
// blocks [391,6641):   x -> bf16 into xbf (NT load x; normal store xbf)
// blocks [6641,6657):  pack w1 into MFMA fragment order
// blocks [6657,6662):  pack w2 likewise
__global__ __launch_bounds__(256) void prepA(
    const float* __restrict__ x, const int* __restrict__ src,
    const int* __restrict__ dst,
    const float* __restrict__ Wr1, const float* __restrict__ Wl1,
    const float* __restrict__ Wr2, const float* __restrict__ Wl2,
    unsigned* __restrict__ bins, unsigned* __restrict__ bin_cnt,
    ushort_t* __restrict__ xbf, ushort_t* __restrict__ w1p,
    ushort_t* __restrict__ w2p) {
    int b = blockIdx.x;
    if (b < 391) {
        __shared__ int lcnt[8];
        __shared__ unsigned lbase[8];
        __shared__ unsigned lbin[8][1024];
        int t = threadIdx.x;
        for (int tile = 0; tile < 2; ++tile) {
            if (t < 8) lcnt[t] = 0;
            __syncthreads();
            int e0 = (b * 2 + tile) * 1024;
#pragma unroll
            for (int k = 0; k < 4; ++k) {
                int e = e0 + k * 256 + t;
                if (e < EDGES) {
                    int d = dst[e], s = src[e];
                    int g = d / GRP;
                    int slot = atomicAdd(&lcnt[g], 1);
                    lbin[g][slot] = ((unsigned)(d - g * GRP) << 16) | (unsigned)s;
                }
            }
            __syncthreads();
            if (t < 8) lbase[t] = atomicAdd(&bin_cnt[t], (unsigned)lcnt[t]);
            __syncthreads();
            for (int g = 0; g < 8; ++g) {
                int cnt = lcnt[g];
                unsigned base = lbase[g];
                for (int i = t; i < cnt; i += 256) {
                    unsigned idx = base + i;
                    if (idx < BINCAP)
                        bins[(size_t)g * BINCAP + idx] = lbin[g][i];
                }
            }
            __syncthreads();
        }
    } else if (b < 6641) {                // 6250*256 == NODES*32 exactly
        int idx = (b - 391) * 256 + threadIdx.x;
        int i = idx >> 5, c = idx & 31;
        f32x4 v = __builtin_nontemporal_load(
            reinterpret_cast<const f32x4*>(x + (size_t)i * 128 + c * 4));
        u16x4 h;
        h[0] = f2bf(v[0]); h[1] = f2bf(v[1]); h[2] = f2bf(v[2]); h[3] = f2bf(v[3]);
        *reinterpret_cast<u16x4*>(xbf + (size_t)i * 128 + c * 4) = h;
    } else if (b < 6657) {                // 4096 threads: w1 fragment pack
        int t = (b - 6641) * 256 + threadIdx.x;     // t = (nf*8+kc)*64+lane
        int nf = t >> 9, kc = (t >> 6) & 7, lane = t & 63;
        int r = nf * 16 + (lane & 15);
        int k2 = kc * 32 + ((lane >> 4) << 3);
        u16x8 o;
#pragma unroll
        for (int j = 0; j < 8; ++j) {
            int kk = k2 + j;
            float v = (kk < 128) ? Wr1[r * 128 + kk] : Wl1[r * 128 + (kk - 128)];
            o[j] = f2bf(v);
        }
        *reinterpret_cast<u16x8*>(w1p + (size_t)t * 8) = o;
    } else {                              // 1280 threads: w2 fragment pack
        int t = (b - 6657) * 256 + threadIdx.x;     // t = (nf*4+kc)*64+lane
        if (t >= 1280) return;
        int nf = t >> 8, kc = (t >> 6) & 3, lane = t & 63;
        int r = nf * 16 + (lane & 15);
        int k2 = kc * 32 + ((lane >> 4) << 3);
        u16x8 o;
#pragma unroll
        for (int j = 0; j < 8; ++j) {
            int kk = k2 + j;
            float v = (r < 40) ? Wr2[r * 128 + kk] : Wl2[(r - 40) * 128 + kk];
            o[j] = f2bf(v);
        }
        *reinterpret_cast<u16x8*>(w2p + (size_t)t * 8) = o;
    }
}

// ---------------- prepB: XCD-local bucket fill from bins ----------------
__global__ __launch_bounds__(256) void prepB(
    const unsigned* __restrict__ bins, const unsigned* __restrict__ bin_cnt,
    int* __restrict__ deg, ushort_t* __restrict__ esrc) {
    int g = blockIdx.x & 7, chunk = blockIdx.x >> 3;   // 49 chunks per group
    unsigned cnt = bin_cnt[g];
    if (cnt > BINCAP) cnt = BINCAP;
    const unsigned* bp = bins + (size_t)g * BINCAP;
    int base = g * GRP;
    for (unsigned i = chunk * 256 + threadIdx.x; i < cnt; i += 49 * 256) {
        unsigned pk = bp[i];
        int d = base + (int)(pk >> 16);
        int s = (int)(pk & 0xffffu);
        int p = atomicAdd(&deg[d], 1);
        if (p < CAP) esrc[(size_t)d * CAP + p] = (ushort_t)s;
    }
}

// ---------------- layer-1 gather-mean (bf16), MLP-unrolled ----------------
__global__ __launch_bounds__(256) void aggx(
    const ushort_t* __restrict__ xbf, ushort_t* __restrict__ mbf,
    const ushort_t* __restrict__ esrc, const int* __restrict__ deg) {
    int idx = blockIdx.x * 256 + threadIdx.x;
    int i = idx >> 4, c = idx & 15;
    if (i >= NODES) return;
    int dg = deg[i];
    int n = dg < CAP ? dg : CAP;
    const ushort_t* ep = esrc + (size_t)i * CAP;
    float a0[8] = {}, a1[8] = {};
    int j = 0;
    for (; j + 4 <= n; j += 4) {
        int s0 = ep[j], s1 = ep[j + 1], s2 = ep[j + 2], s3 = ep[j + 3];
        u16x8 v0 = *reinterpret_cast<const u16x8*>(xbf + (size_t)s0 * 128 + c * 8);
        u16x8 v1 = *reinterpret_cast<const u16x8*>(xbf + (size_t)s1 * 128 + c * 8);
        u16x8 v2 = *reinterpret_cast<const u16x8*>(xbf + (size_t)s2 * 128 + c * 8);
        u16x8 v3 = *reinterpret_cast<const u16x8*>(xbf + (size_t)s3 * 128 + c * 8);
#pragma unroll
        for (int k = 0; k < 8; ++k) {
            a0[k] += bf2f(v0[k]) + bf2f(v2[k]);
            a1[k] += bf2f(v1[k]) + bf2f(v3[k]);
        }
    }
    for (; j < n; ++j) {
        int s = ep[j];
        u16x8 v = *reinterpret_cast<const u16x8*>(xbf + (size_t)s * 128 + c * 8);
#pragma unroll
        for (int k = 0; k < 8; ++k) a0[k] += bf2f(v[k]);
    }
    float ci = 1.0f / fmaxf((float)dg, 1.0f);
    u16x8 m;
#pragma unroll
    for (int k = 0; k < 8; ++k) m[k] = f2bf((a0[k] + a1[k]) * ci);
    *reinterpret_cast<u16x8*>(mbf + (size_t)i * 128 + c * 8) = m;
}

// ---------------- fused GEMM1 + GEMM2 (packed weights, split A) ----------------
__global__ __launch_bounds__(256) void gemm12(
    const ushort_t* __restrict__ xbf, const ushort_t* __restrict__ mbf,
    const ushort_t* __restrict__ w1p, const ushort_t* __restrict__ w2p,
    const float* __restrict__ b1, float* __restrict__ emb,
    ushort_t* __restrict__ V, int M) {
    __shared__ ushort_t hs[64][136];      // stride 136: 16B-aligned rows
    const int wave = threadIdx.x >> 6, lane = threadIdx.x & 63;
    const int r0 = blockIdx.x * 64 + wave * 16;
    int arow = r0 + (lane & 15); if (arow >= M) arow = M - 1;
    const int klane = (lane >> 4) * 8;

    f32x4 acc[8] = {};
#pragma unroll
    for (int kc = 0; kc < 8; ++kc) {
        const ushort_t* abase = (kc < 4) ? xbf : mbf;
        bf16x8 a = *reinterpret_cast<const bf16x8*>(
            abase + (size_t)arow * 128 + (kc & 3) * 32 + klane);
        bf16x8 wv[8];
#pragma unroll
        for (int nf = 0; nf < 8; ++nf)
            wv[nf] = *reinterpret_cast<const bf16x8*>(
                w1p + (size_t)((nf * 8 + kc) * 64 + lane) * 8);
#pragma unroll
        for (int nf = 0; nf < 8; ++nf)
            acc[nf] = __builtin_amdgcn_mfma_f32_16x16x32_bf16(a, wv[nf], acc[nf], 0, 0, 0);
    }

    const int crow0r = wave * 16 + (lane >> 4) * 4;     // row within tile
    const int crow0  = blockIdx.x * 64 + crow0r;
    const int ccol   = lane & 15;
#pragma unroll
    for (int nf = 0; nf < 8; ++nf) {
        int col = nf * 16 + ccol;
        float bv = b1[col];
#pragma unroll
        for (int r = 0; r < 4; ++r) {
            int row = crow0 + r;
            float val = acc[nf][r] + bv;
            if (row < M)
                __builtin_nontemporal_store(val, emb + (size_t)row * 128 + col);
            hs[crow0r + r][col] = f2bf(fmaxf(val, 0.f));
        }
    }
    __syncthreads();

    f32x4 acc2[5] = {};
#pragma unroll
    for (int kc = 0; kc < 4; ++kc) {
        bf16x8 a = *reinterpret_cast<const bf16x8*>(
            &hs[wave * 16 + (lane & 15)][kc * 32 + klane]);
        bf16x8 wv[5];
#pragma unroll
        for (int nf = 0; nf < 5; ++nf)
            wv[nf] = *reinterpret_cast<const bf16x8*>(
                w2p + (size_t)((nf * 4 + kc) * 64 + lane) * 8);
#pragma unroll
        for (int nf = 0; nf < 5; ++nf)
            acc2[nf] = __builtin_amdgcn_mfma_f32_16x16x32_bf16(a, wv[nf], acc2[nf], 0, 0, 0);
    }
#pragma unroll
    for (int nf = 0; nf < 5; ++nf) {
        int col = nf * 16 + ccol;
#pragma unroll
        for (int r = 0; r < 4; ++r) {
            int row = crow0 + r;
            if (row < M) V[(size_t)row * 80 + col] = f2bf(acc2[nf][r]);
        }
    }
}

// ---------------- layer-2 gather-mean + epilogue (bf16 V), MLP-unrolled ----------------
__global__ __launch_bounds__(256) void agg2(
    const ushort_t* __restrict__ V, const ushort_t* __restrict__ esrc,
    const int* __restrict__ deg, const float* __restrict__ b2,
    float* __restrict__ logits) {
    int idx = blockIdx.x * 256 + threadIdx.x;
    int i = idx >> 3, c = idx & 7;
    if (i >= NODES || c >= 5) return;
    int dg = deg[i];
    int n = dg < CAP ? dg : CAP;
    const ushort_t* ep = esrc + (size_t)i * CAP;
    float a0[8] = {}, a1[8] = {};
    int j = 0;
    for (; j + 4 <= n; j += 4) {
        int s0 = ep[j], s1 = ep[j + 1], s2 = ep[j + 2], s3 = ep[j + 3];
        u16x8 v0 = *reinterpret_cast<const u16x8*>(V + (size_t)s0 * 80 + 40 + c * 8);
        u16x8 v1 = *reinterpret_cast<const u16x8*>(V + (size_t)s1 * 80 + 40 + c * 8);
        u16x8 v2 = *reinterpret_cast<const u16x8*>(V + (size_t)s2 * 80 + 40 + c * 8);
        u16x8 v3 = *reinterpret_cast<const u16x8*>(V + (size_t)s3 * 80 + 40 + c * 8);
#pragma unroll
        for (int k = 0; k < 8; ++k) {
            a0[k] += bf2f(v0[k]) + bf2f(v2[k]);
            a1[k] += bf2f(v1[k]) + bf2f(v3[k]);
        }
    }
    for (; j < n; ++j) {
        int s = ep[j];
        u16x8 v = *reinterpret_cast<const u16x8*>(V + (size_t)s * 80 + 40 + c * 8);
#pragma unroll
        for (int k = 0; k < 8; ++k) a0[k] += bf2f(v[k]);
    }
    float ci = 1.0f / fmaxf((float)dg, 1.0f);
    u16x8 sv = *reinterpret_cast<const u16x8*>(V + (size_t)i * 80 + c * 8);
    float o[8];
#pragma unroll
    for (int k = 0; k < 8; ++k)
        o[k] = bf2f(sv[k]) + (a0[k] + a1[k]) * ci + b2[c * 8 + k];
    float4* dst4 = reinterpret_cast<float4*>(logits + (size_t)i * 40 + c * 8);
    dst4[0] = make_float4(o[0], o[1], o[2], o[3]);
    dst4[1] = make_float4(o[4], o[5], o[6], o[7]);
}

extern "C" void kernel_launch(void* const* d_in, const int* in_sizes, int n_in,
                              void* d_out, int out_size, void* d_ws, size_t ws_size,
                              hipStream_t stream) {
    const float* x   = (const float*)d_in[0];
    const int*   ei  = (const int*)d_in[1];
    const float* Wl1 = (const float*)d_in[2];
    const float* Wr1 = (const float*)d_in[3];
    const float* b1  = (const float*)d_in[4];
    const float* Wl2 = (const float*)d_in[5];
    const float* Wr2 = (const float*)d_in[6];
    const float* b2  = (const float*)d_in[7];
    const int* src = ei;              // edge_index[0]
    const int* dst = ei + EDGES;      // edge_index[1]

    // Workspace (~44.5 MB):
    //   [0, 12.8M)          xbf [50000x128 bf16]
    //   [12.8M, 25.6M)      mbf [50000x128 bf16]
    //   [25.6M, 33.6M)      V   [50000x80 bf16]
    //   [33.6M, 40.0M)      esrc [50000*64 ushort]
    //   [40.0M, 40.2M)      deg [50000 int] + bin_cnt [8 u32]
    //   [40.200064M, ...)   w1p, w2p (packed bf16)
    //   [40.28608M, 44.5M)  bins [8 x 131072 u32]
    char* ws = (char*)d_ws;
    ushort_t* xbf     = (ushort_t*)ws;
    ushort_t* mbf     = (ushort_t*)(ws + 12800000);
    ushort_t* V       = (ushort_t*)(ws + 25600000);
    ushort_t* esrc    = (ushort_t*)(ws + 33600000);
    int*      deg     = (int*)(ws + 40000000);
    unsigned* bin_cnt = (unsigned*)(ws + 40200000);
    ushort_t* w1p     = (ushort_t*)(ws + 40200064);
    ushort_t* w2p     = (ushort_t*)(ws + 40265600);
    unsigned* bins    = (unsigned*)(ws + 40286080);

    float* logits_out = (float*)d_out;                   // 50000*40 f32
    float* emb_out    = logits_out + (size_t)NODES * 40; // 50000*128 f32

    zerok<<<98, 256, 0, stream>>>(deg, bin_cnt);

    prepA<<<6662, 256, 0, stream>>>(x, src, dst, Wr1, Wl1, Wr2, Wl2,
                                    bins, bin_cnt, xbf, w1p, w2p);

    prepB<<<392, 256, 0, stream>>>(bins, bin_cnt, deg, esrc);

    aggx<<<3125, 256, 0, stream>>>(xbf, mbf, esrc, deg);

    gemm12<<<(NODES + 63) / 64, 256, 0, stream>>>(xbf, mbf, w1p, w2p, b1,
                                                  emb_out, V, NODES);

    agg2<<<(NODES * 8 + 255) / 256, 256, 0, stream>>>(V, esrc, deg, b2, logits_out);
}

// Round 13
// 126.458 us; speedup vs baseline: 1.0550x; 1.0544x over previous
//
#include <hip/hip_runtime.h>
#include <hip/hip_bf16.h>
#include <stdint.h>

#define NODES 50000
#define EDGES 800000
#define CAP   64        // per-node bucket capacity (deg ~ Poisson(16), max<64 verified by pass)

typedef __attribute__((ext_vector_type(8))) short bf16x8;
typedef __attribute__((ext_vector_type(8))) unsigned short u16x8;
typedef __attribute__((ext_vector_type(4))) float f32x4;
typedef unsigned short ushort_t;

__device__ __forceinline__ float4 ld4(const float* p) {
    return *reinterpret_cast<const float4*>(p);
}
__device__ __forceinline__ ushort_t f2bf(float f) {   // RNE f32->bf16 bits
    unsigned u = __float_as_uint(f);
    unsigned r = (u + 0x7fff + ((u >> 16) & 1)) >> 16;
    return (ushort_t)r;
}
__device__ __forceinline__ float bf2f(ushort_t h) {
    return __uint_as_float(((unsigned)h) << 16);
}

// ---------------- zero deg (plain kernel; rocclr fill path avoided) ----------------
__global__ __launch_bounds__(256) void zerok(int* __restrict__ deg) {
    int t = blockIdx.x * 256 + threadIdx.x;
    if (t < 25000) reinterpret_cast<int2*>(deg)[t] = make_int2(0, 0);
}

// ---------------- prepCvt: x -> bf16 into A1 cols 0..127, + weight packs ----------------
// Runs BEFORE prepFill so its 38 MB of streaming traffic cannot evict the
// fill's esrc/deg lines mid-fill (the round-8 write-amplification theory).
// blocks [0,6250):     x -> bf16 into A1 cols 0..127 (A1 row stride 256)
// blocks [6250,6266):  pack w1 into MFMA fragment order:
//                      w1p[((nf*8+kc)*64+lane)*8+j] = W1[nf*16+(lane&15)][kc*32+(lane>>4)*8+j]
//                      where W1 = [Wr1 | Wl1] K-concat (128 rows x 256 K)
// blocks [6266,6271):  pack w2 likewise (W2 = [Wr2 ; Wl2], 80 rows x 128 K)
__global__ __launch_bounds__(256) void prepCvt(
    const float* __restrict__ x,
    const float* __restrict__ Wr1, const float* __restrict__ Wl1,
    const float* __restrict__ Wr2, const float* __restrict__ Wl2,
    ushort_t* __restrict__ A1, ushort_t* __restrict__ w1p,
    ushort_t* __restrict__ w2p) {
    int b = blockIdx.x;
    if (b < 6250) {                       // 6250*256 == NODES*32 exactly
        int idx = b * 256 + threadIdx.x;
        int i = idx >> 5, c = idx & 31;
        float4 v = ld4(x + (size_t)i * 128 + c * 4);
        ushort4 h;
        h.x = f2bf(v.x); h.y = f2bf(v.y); h.z = f2bf(v.z); h.w = f2bf(v.w);
        *reinterpret_cast<ushort4*>(A1 + (size_t)i * 256 + c * 4) = h;
    } else if (b < 6266) {                // 4096 threads: w1 fragment pack
        int t = (b - 6250) * 256 + threadIdx.x;     // t = (nf*8+kc)*64+lane
        int nf = t >> 9, kc = (t >> 6) & 7, lane = t & 63;
        int r = nf * 16 + (lane & 15);
        int k2 = kc * 32 + ((lane >> 4) << 3);
        u16x8 o;
#pragma unroll
        for (int j = 0; j < 8; ++j) {
            int kk = k2 + j;
            float v = (kk < 128) ? Wr1[r * 128 + kk] : Wl1[r * 128 + (kk - 128)];
            o[j] = f2bf(v);
        }
        *reinterpret_cast<u16x8*>(w1p + (size_t)t * 8) = o;
    } else {                              // 1280 threads: w2 fragment pack
        int t = (b - 6266) * 256 + threadIdx.x;     // t = (nf*4+kc)*64+lane
        if (t >= 1280) return;
        int nf = t >> 8, kc = (t >> 6) & 3, lane = t & 63;
        int r = nf * 16 + (lane & 15);
        int k2 = kc * 32 + ((lane >> 4) << 3);
        u16x8 o;
#pragma unroll
        for (int j = 0; j < 8; ++j) {
            int kk = k2 + j;
            float v = (r < 40) ? Wr2[r * 128 + kk] : Wl2[(r - 40) * 128 + kk];
            o[j] = f2bf(v);
        }
        *reinterpret_cast<u16x8*>(w2p + (size_t)t * 8) = o;
    }
}

// ---------------- prepFill: XCD-partitioned bucket fill (isolated) ----------------
// Group g = b&7 owns nodes [g*6250,(g+1)*6250); with round-robin block->XCD
// dispatch the group's 800 KB esrc slice + 25 KB deg slice stays in one L2.
// Each group streams all edges (chunk = b>>3, 2048 edges/chunk) and filters.
__global__ __launch_bounds__(256) void prepFill(
    const int* __restrict__ src, const int* __restrict__ dst,
    int* __restrict__ deg, ushort_t* __restrict__ esrc) {
    int g = blockIdx.x & 7, chunk = blockIdx.x >> 3;
    int lo = g * 6250;
#pragma unroll
    for (int k = 0; k < 8; ++k) {
        int e = chunk * 2048 + k * 256 + threadIdx.x;
        if (e < EDGES) {
            int d = dst[e];
            if ((unsigned)(d - lo) < 6250u) {
                int s = src[e];
                int p = atomicAdd(&deg[d], 1);
                if (p < CAP) esrc[(size_t)d * CAP + p] = (ushort_t)s;
            }
        }
    }
}

// ---------------- layer-1 gather-mean (bf16), MLP-unrolled ----------------
// 16 lanes/node, ushort8 (16B) per lane; 4 neighbors in flight, 2 acc chains.
__global__ __launch_bounds__(256) void aggx(
    ushort_t* __restrict__ A1, const ushort_t* __restrict__ esrc,
    const int* __restrict__ deg) {
    int idx = blockIdx.x * 256 + threadIdx.x;
    int i = idx >> 4, c = idx & 15;
    if (i >= NODES) return;
    int dg = deg[i];
    int n = dg < CAP ? dg : CAP;
    const ushort_t* ep = esrc + (size_t)i * CAP;
    float a0[8] = {}, a1[8] = {};
    int j = 0;
    for (; j + 4 <= n; j += 4) {
        int s0 = ep[j], s1 = ep[j + 1], s2 = ep[j + 2], s3 = ep[j + 3];
        u16x8 v0 = *reinterpret_cast<const u16x8*>(A1 + (size_t)s0 * 256 + c * 8);
        u16x8 v1 = *reinterpret_cast<const u16x8*>(A1 + (size_t)s1 * 256 + c * 8);
        u16x8 v2 = *reinterpret_cast<const u16x8*>(A1 + (size_t)s2 * 256 + c * 8);
        u16x8 v3 = *reinterpret_cast<const u16x8*>(A1 + (size_t)s3 * 256 + c * 8);
#pragma unroll
        for (int k = 0; k < 8; ++k) {
            a0[k] += bf2f(v0[k]) + bf2f(v2[k]);
            a1[k] += bf2f(v1[k]) + bf2f(v3[k]);
        }
    }
    for (; j < n; ++j) {
        int s = ep[j];
        u16x8 v = *reinterpret_cast<const u16x8*>(A1 + (size_t)s * 256 + c * 8);
#pragma unroll
        for (int k = 0; k < 8; ++k) a0[k] += bf2f(v[k]);
    }
    float ci = 1.0f / fmaxf((float)dg, 1.0f);
    u16x8 m;
#pragma unroll
    for (int k = 0; k < 8; ++k) m[k] = f2bf((a0[k] + a1[k]) * ci);
    *reinterpret_cast<u16x8*>(A1 + (size_t)i * 256 + 128 + c * 8) = m;
}

// ---------------- fused GEMM1 + GEMM2 (packed weights) ----------------
// Phase 1: emb[64 rows x 128] = A1[rows,256] @ W1^T + b1; relu->bf16 LDS tile
// Phase 2: V[rows x 80] = h_lds[rows,128] @ W2^T -> bf16
__global__ __launch_bounds__(256) void gemm12(
    const ushort_t* __restrict__ A1, const ushort_t* __restrict__ w1p,
    const ushort_t* __restrict__ w2p, const float* __restrict__ b1,
    float* __restrict__ emb, ushort_t* __restrict__ V, int M) {
    __shared__ ushort_t hs[64][136];      // stride 136: 16B-aligned rows
    const int wave = threadIdx.x >> 6, lane = threadIdx.x & 63;
    const int r0 = blockIdx.x * 64 + wave * 16;
    int arow = r0 + (lane & 15); if (arow >= M) arow = M - 1;
    const int klane = (lane >> 4) * 8;

    f32x4 acc[8] = {};
#pragma unroll
    for (int kc = 0; kc < 8; ++kc) {
        bf16x8 a = *reinterpret_cast<const bf16x8*>(A1 + (size_t)arow * 256 + kc * 32 + klane);
        bf16x8 wv[8];
#pragma unroll
        for (int nf = 0; nf < 8; ++nf)
            wv[nf] = *reinterpret_cast<const bf16x8*>(
                w1p + (size_t)((nf * 8 + kc) * 64 + lane) * 8);
#pragma unroll
        for (int nf = 0; nf < 8; ++nf)
            acc[nf] = __builtin_amdgcn_mfma_f32_16x16x32_bf16(a, wv[nf], acc[nf], 0, 0, 0);
    }

    const int crow0r = wave * 16 + (lane >> 4) * 4;     // row within tile
    const int crow0  = blockIdx.x * 64 + crow0r;
    const int ccol   = lane & 15;
#pragma unroll
    for (int nf = 0; nf < 8; ++nf) {
        int col = nf * 16 + ccol;
        float bv = b1[col];
#pragma unroll
        for (int r = 0; r < 4; ++r) {
            int row = crow0 + r;
            float val = acc[nf][r] + bv;
            if (row < M) emb[(size_t)row * 128 + col] = val;
            hs[crow0r + r][col] = f2bf(fmaxf(val, 0.f));
        }
    }
    __syncthreads();

    f32x4 acc2[5] = {};
#pragma unroll
    for (int kc = 0; kc < 4; ++kc) {
        bf16x8 a = *reinterpret_cast<const bf16x8*>(
            &hs[wave * 16 + (lane & 15)][kc * 32 + klane]);
        bf16x8 wv[5];
#pragma unroll
        for (int nf = 0; nf < 5; ++nf)
            wv[nf] = *reinterpret_cast<const bf16x8*>(
                w2p + (size_t)((nf * 4 + kc) * 64 + lane) * 8);
#pragma unroll
        for (int nf = 0; nf < 5; ++nf)
            acc2[nf] = __builtin_amdgcn_mfma_f32_16x16x32_bf16(a, wv[nf], acc2[nf], 0, 0, 0);
    }
#pragma unroll
    for (int nf = 0; nf < 5; ++nf) {
        int col = nf * 16 + ccol;
#pragma unroll
        for (int r = 0; r < 4; ++r) {
            int row = crow0 + r;
            if (row < M) V[(size_t)row * 80 + col] = f2bf(acc2[nf][r]);
        }
    }
}

// ---------------- layer-2 gather-mean + epilogue (bf16 V), MLP-unrolled ----------------
// 8 lanes/node, lanes 0..4 carry ushort8 (40 cols); logits = self + mean + b2.
__global__ __launch_bounds__(256) void agg2(
    const ushort_t* __restrict__ V, const ushort_t* __restrict__ esrc,
    const int* __restrict__ deg, const float* __restrict__ b2,
    float* __restrict__ logits) {
    int idx = blockIdx.x * 256 + threadIdx.x;
    int i = idx >> 3, c = idx & 7;
    if (i >= NODES || c >= 5) return;
    int dg = deg[i];
    int n = dg < CAP ? dg : CAP;
    const ushort_t* ep = esrc + (size_t)i * CAP;
    float a0[8] = {}, a1[8] = {};
    int j = 0;
    for (; j + 4 <= n; j += 4) {
        int s0 = ep[j], s1 = ep[j + 1], s2 = ep[j + 2], s3 = ep[j + 3];
        u16x8 v0 = *reinterpret_cast<const u16x8*>(V + (size_t)s0 * 80 + 40 + c * 8);
        u16x8 v1 = *reinterpret_cast<const u16x8*>(V + (size_t)s1 * 80 + 40 + c * 8);
        u16x8 v2 = *reinterpret_cast<const u16x8*>(V + (size_t)s2 * 80 + 40 + c * 8);
        u16x8 v3 = *reinterpret_cast<const u16x8*>(V + (size_t)s3 * 80 + 40 + c * 8);
#pragma unroll
        for (int k = 0; k < 8; ++k) {
            a0[k] += bf2f(v0[k]) + bf2f(v2[k]);
            a1[k] += bf2f(v1[k]) + bf2f(v3[k]);
        }
    }
    for (; j < n; ++j) {
        int s = ep[j];
        u16x8 v = *reinterpret_cast<const u16x8*>(V + (size_t)s * 80 + 40 + c * 8);
#pragma unroll
        for (int k = 0; k < 8; ++k) a0[k] += bf2f(v[k]);
    }
    float ci = 1.0f / fmaxf((float)dg, 1.0f);
    u16x8 sv = *reinterpret_cast<const u16x8*>(V + (size_t)i * 80 + c * 8);
    float o[8];
#pragma unroll
    for (int k = 0; k < 8; ++k)
        o[k] = bf2f(sv[k]) + (a0[k] + a1[k]) * ci + b2[c * 8 + k];
    float4* dst4 = reinterpret_cast<float4*>(logits + (size_t)i * 40 + c * 8);
    dst4[0] = make_float4(o[0], o[1], o[2], o[3]);
    dst4[1] = make_float4(o[4], o[5], o[6], o[7]);
}

extern "C" void kernel_launch(void* const* d_in, const int* in_sizes, int n_in,
                              void* d_out, int out_size, void* d_ws, size_t ws_size,
                              hipStream_t stream) {
    const float* x   = (const float*)d_in[0];
    const int*   ei  = (const int*)d_in[1];
    const float* Wl1 = (const float*)d_in[2];
    const float* Wr1 = (const float*)d_in[3];
    const float* b1  = (const float*)d_in[4];
    const float* Wl2 = (const float*)d_in[5];
    const float* Wr2 = (const float*)d_in[6];
    const float* b2  = (const float*)d_in[7];
    const int* src = ei;              // edge_index[0]
    const int* dst = ei + EDGES;      // edge_index[1]

    // Workspace (~40.3 MB):
    //   [0, 25.6M)       A1 [50000x256 bf16] = [xbf | mbf]
    //   [25.6M, 33.6M)   V  [50000x80 bf16]
    //   [33.6M, 40.0M)   esrc [50000*64 ushort]
    //   [40.0M, 40.2M)   deg [50000 int]
    //   [40.2M, ...)     w1p [32768 bf16 packed], w2p [10240 bf16 packed]
    char* ws = (char*)d_ws;
    ushort_t* A1   = (ushort_t*)ws;
    ushort_t* V    = (ushort_t*)(ws + 25600000);
    ushort_t* esrc = (ushort_t*)(ws + 33600000);
    int*      deg  = (int*)(ws + 40000000);
    ushort_t* w1p  = (ushort_t*)(ws + 40200000);
    ushort_t* w2p  = (ushort_t*)(ws + 40265536);

    float* logits_out = (float*)d_out;                   // 50000*40 f32
    float* emb_out    = logits_out + (size_t)NODES * 40; // 50000*128 f32

    zerok<<<98, 256, 0, stream>>>(deg);

    prepCvt<<<6271, 256, 0, stream>>>(x, Wr1, Wl1, Wr2, Wl2, A1, w1p, w2p);

    prepFill<<<3128, 256, 0, stream>>>(src, dst, deg, esrc);

    aggx<<<3125, 256, 0, stream>>>(A1, esrc, deg);

    gemm12<<<(NODES + 63) / 64, 256, 0, stream>>>(A1, w1p, w2p, b1, emb_out, V, NODES);

    agg2<<<(NODES * 8 + 255) / 256, 256, 0, stream>>>(V, esrc, deg, b2, logits_out);
}

// Round 14
// 119.250 us; speedup vs baseline: 1.1187x; 1.0604x over previous
//
#include <hip/hip_runtime.h>
#include <hip/hip_bf16.h>
#include <stdint.h>

#define NODES 50000
#define EDGES 800000
#define CAP   64        // per-node bucket capacity (deg ~ Poisson(16))

typedef __attribute__((ext_vector_type(8))) short bf16x8;
typedef __attribute__((ext_vector_type(8))) unsigned short u16x8;
typedef __attribute__((ext_vector_type(4))) float f32x4;
typedef unsigned short ushort_t;

__device__ __forceinline__ float4 ld4(const float* p) {
    return *reinterpret_cast<const float4*>(p);
}
__device__ __forceinline__ ushort_t f2bf(float f) {   // RNE f32->bf16 bits
    unsigned u = __float_as_uint(f);
    unsigned r = (u + 0x7fff + ((u >> 16) & 1)) >> 16;
    return (ushort_t)r;
}
__device__ __forceinline__ float bf2f(ushort_t h) {
    return __uint_as_float(((unsigned)h) << 16);
}

// ---------------- zero deg (plain kernel; rocclr fill path avoided) ----------------
__global__ __launch_bounds__(256) void zerok(int* __restrict__ deg) {
    int t = blockIdx.x * 256 + threadIdx.x;
    if (t < 25000) reinterpret_cast<int2*>(deg)[t] = make_int2(0, 0);
}

// ---------------- monolithic prep (R7 structure: fill ∥ cvt ∥ packs) ----------------
// blocks [0,3128):      XCD-partitioned bucket fill (group g = b&7 owns nodes
//                       [g*6250,(g+1)*6250); round-robin block->XCD keeps each
//                       group's esrc/deg slice in one L2)
// blocks [3128,9378):   x -> bf16 into A1 cols 0..127 (overlaps with fill)
// blocks [9378,9394):   pack w1 into MFMA fragment order
// blocks [9394,9399):   pack w2 likewise
__global__ __launch_bounds__(256) void prep(
    const float* __restrict__ x, const int* __restrict__ src,
    const int* __restrict__ dst,
    const float* __restrict__ Wr1, const float* __restrict__ Wl1,
    const float* __restrict__ Wr2, const float* __restrict__ Wl2,
    int* __restrict__ deg, ushort_t* __restrict__ esrc,
    ushort_t* __restrict__ A1, ushort_t* __restrict__ w1p,
    ushort_t* __restrict__ w2p) {
    int b = blockIdx.x;
    if (b < 3128) {                       // 391 chunks x 8 groups
        int g = b & 7, chunk = b >> 3;
        int lo = g * 6250;
#pragma unroll
        for (int k = 0; k < 8; ++k) {
            int e = chunk * 2048 + k * 256 + threadIdx.x;
            if (e < EDGES) {
                int d = dst[e];
                if ((unsigned)(d - lo) < 6250u) {
                    int s = src[e];
                    int p = atomicAdd(&deg[d], 1);
                    if (p < CAP) esrc[(size_t)d * CAP + p] = (ushort_t)s;
                }
            }
        }
    } else if (b < 9378) {                // 6250*256 == NODES*32 exactly
        int idx = (b - 3128) * 256 + threadIdx.x;
        int i = idx >> 5, c = idx & 31;
        float4 v = ld4(x + (size_t)i * 128 + c * 4);
        ushort4 h;
        h.x = f2bf(v.x); h.y = f2bf(v.y); h.z = f2bf(v.z); h.w = f2bf(v.w);
        *reinterpret_cast<ushort4*>(A1 + (size_t)i * 256 + c * 4) = h;
    } else if (b < 9394) {                // 4096 threads: w1 fragment pack
        int t = (b - 9378) * 256 + threadIdx.x;     // t = (nf*8+kc)*64+lane
        int nf = t >> 9, kc = (t >> 6) & 7, lane = t & 63;
        int r = nf * 16 + (lane & 15);
        int k2 = kc * 32 + ((lane >> 4) << 3);
        u16x8 o;
#pragma unroll
        for (int j = 0; j < 8; ++j) {
            int kk = k2 + j;
            float v = (kk < 128) ? Wr1[r * 128 + kk] : Wl1[r * 128 + (kk - 128)];
            o[j] = f2bf(v);
        }
        *reinterpret_cast<u16x8*>(w1p + (size_t)t * 8) = o;
    } else {                              // 1280 threads: w2 fragment pack
        int t = (b - 9394) * 256 + threadIdx.x;     // t = (nf*4+kc)*64+lane
        if (t >= 1280) return;
        int nf = t >> 8, kc = (t >> 6) & 3, lane = t & 63;
        int r = nf * 16 + (lane & 15);
        int k2 = kc * 32 + ((lane >> 4) << 3);
        u16x8 o;
#pragma unroll
        for (int j = 0; j < 8; ++j) {
            int kk = k2 + j;
            float v = (r < 40) ? Wr2[r * 128 + kk] : Wl2[(r - 40) * 128 + kk];
            o[j] = f2bf(v);
        }
        *reinterpret_cast<u16x8*>(w2p + (size_t)t * 8) = o;
    }
}

// ---------------- layer-1 gather-mean (bf16), 8-deep MLP ----------------
// 16 lanes/node, ushort8 (16B) per lane; 8 neighbors in flight, 2 acc chains.
__global__ __launch_bounds__(256) void aggx(
    ushort_t* __restrict__ A1, const ushort_t* __restrict__ esrc,
    const int* __restrict__ deg) {
    int idx = blockIdx.x * 256 + threadIdx.x;
    int i = idx >> 4, c = idx & 15;
    int dg = deg[i];
    int n = dg < CAP ? dg : CAP;
    const ushort_t* ep = esrc + (size_t)i * CAP;
    float a0[8] = {}, a1[8] = {};
    int j = 0;
    for (; j + 8 <= n; j += 8) {
        int s0 = ep[j],     s1 = ep[j + 1], s2 = ep[j + 2], s3 = ep[j + 3];
        int s4 = ep[j + 4], s5 = ep[j + 5], s6 = ep[j + 6], s7 = ep[j + 7];
        u16x8 v0 = *reinterpret_cast<const u16x8*>(A1 + (size_t)s0 * 256 + c * 8);
        u16x8 v1 = *reinterpret_cast<const u16x8*>(A1 + (size_t)s1 * 256 + c * 8);
        u16x8 v2 = *reinterpret_cast<const u16x8*>(A1 + (size_t)s2 * 256 + c * 8);
        u16x8 v3 = *reinterpret_cast<const u16x8*>(A1 + (size_t)s3 * 256 + c * 8);
        u16x8 v4 = *reinterpret_cast<const u16x8*>(A1 + (size_t)s4 * 256 + c * 8);
        u16x8 v5 = *reinterpret_cast<const u16x8*>(A1 + (size_t)s5 * 256 + c * 8);
        u16x8 v6 = *reinterpret_cast<const u16x8*>(A1 + (size_t)s6 * 256 + c * 8);
        u16x8 v7 = *reinterpret_cast<const u16x8*>(A1 + (size_t)s7 * 256 + c * 8);
#pragma unroll
        for (int k = 0; k < 8; ++k) {
            a0[k] += (bf2f(v0[k]) + bf2f(v2[k])) + (bf2f(v4[k]) + bf2f(v6[k]));
            a1[k] += (bf2f(v1[k]) + bf2f(v3[k])) + (bf2f(v5[k]) + bf2f(v7[k]));
        }
    }
    for (; j + 4 <= n; j += 4) {
        int s0 = ep[j], s1 = ep[j + 1], s2 = ep[j + 2], s3 = ep[j + 3];
        u16x8 v0 = *reinterpret_cast<const u16x8*>(A1 + (size_t)s0 * 256 + c * 8);
        u16x8 v1 = *reinterpret_cast<const u16x8*>(A1 + (size_t)s1 * 256 + c * 8);
        u16x8 v2 = *reinterpret_cast<const u16x8*>(A1 + (size_t)s2 * 256 + c * 8);
        u16x8 v3 = *reinterpret_cast<const u16x8*>(A1 + (size_t)s3 * 256 + c * 8);
#pragma unroll
        for (int k = 0; k < 8; ++k) {
            a0[k] += bf2f(v0[k]) + bf2f(v2[k]);
            a1[k] += bf2f(v1[k]) + bf2f(v3[k]);
        }
    }
    for (; j < n; ++j) {
        int s = ep[j];
        u16x8 v = *reinterpret_cast<const u16x8*>(A1 + (size_t)s * 256 + c * 8);
#pragma unroll
        for (int k = 0; k < 8; ++k) a0[k] += bf2f(v[k]);
    }
    float ci = 1.0f / fmaxf((float)dg, 1.0f);
    u16x8 m;
#pragma unroll
    for (int k = 0; k < 8; ++k) m[k] = f2bf((a0[k] + a1[k]) * ci);
    *reinterpret_cast<u16x8*>(A1 + (size_t)i * 256 + 128 + c * 8) = m;
}

// ---------------- fused GEMM1 + GEMM2 (packed weights) ----------------
// Phase 1: emb[64 rows x 128] = A1[rows,256] @ W1^T + b1; relu->bf16 LDS tile
//          emb stored NT (never re-read on device -> keep V/esrc in L2)
// Phase 2: V[rows x 80] = h_lds[rows,128] @ W2^T -> bf16
__global__ __launch_bounds__(256) void gemm12(
    const ushort_t* __restrict__ A1, const ushort_t* __restrict__ w1p,
    const ushort_t* __restrict__ w2p, const float* __restrict__ b1,
    float* __restrict__ emb, ushort_t* __restrict__ V, int M) {
    __shared__ ushort_t hs[64][136];      // stride 136: 16B-aligned rows
    const int wave = threadIdx.x >> 6, lane = threadIdx.x & 63;
    const int r0 = blockIdx.x * 64 + wave * 16;
    int arow = r0 + (lane & 15); if (arow >= M) arow = M - 1;
    const int klane = (lane >> 4) * 8;

    f32x4 acc[8] = {};
#pragma unroll
    for (int kc = 0; kc < 8; ++kc) {
        bf16x8 a = *reinterpret_cast<const bf16x8*>(A1 + (size_t)arow * 256 + kc * 32 + klane);
        bf16x8 wv[8];
#pragma unroll
        for (int nf = 0; nf < 8; ++nf)
            wv[nf] = *reinterpret_cast<const bf16x8*>(
                w1p + (size_t)((nf * 8 + kc) * 64 + lane) * 8);
#pragma unroll
        for (int nf = 0; nf < 8; ++nf)
            acc[nf] = __builtin_amdgcn_mfma_f32_16x16x32_bf16(a, wv[nf], acc[nf], 0, 0, 0);
    }

    const int crow0r = wave * 16 + (lane >> 4) * 4;     // row within tile
    const int crow0  = blockIdx.x * 64 + crow0r;
    const int ccol   = lane & 15;
#pragma unroll
    for (int nf = 0; nf < 8; ++nf) {
        int col = nf * 16 + ccol;
        float bv = b1[col];
#pragma unroll
        for (int r = 0; r < 4; ++r) {
            int row = crow0 + r;
            float val = acc[nf][r] + bv;
            if (row < M)
                __builtin_nontemporal_store(val, emb + (size_t)row * 128 + col);
            hs[crow0r + r][col] = f2bf(fmaxf(val, 0.f));
        }
    }
    __syncthreads();

    f32x4 acc2[5] = {};
#pragma unroll
    for (int kc = 0; kc < 4; ++kc) {
        bf16x8 a = *reinterpret_cast<const bf16x8*>(
            &hs[wave * 16 + (lane & 15)][kc * 32 + klane]);
        bf16x8 wv[5];
#pragma unroll
        for (int nf = 0; nf < 5; ++nf)
            wv[nf] = *reinterpret_cast<const bf16x8*>(
                w2p + (size_t)((nf * 4 + kc) * 64 + lane) * 8);
#pragma unroll
        for (int nf = 0; nf < 5; ++nf)
            acc2[nf] = __builtin_amdgcn_mfma_f32_16x16x32_bf16(a, wv[nf], acc2[nf], 0, 0, 0);
    }
#pragma unroll
    for (int nf = 0; nf < 5; ++nf) {
        int col = nf * 16 + ccol;
#pragma unroll
        for (int r = 0; r < 4; ++r) {
            int row = crow0 + r;
            if (row < M) V[(size_t)row * 80 + col] = f2bf(acc2[nf][r]);
        }
    }
}

// ---------------- layer-2 gather-mean + epilogue (bf16 V), 8-deep MLP ----------------
// 8 lanes/node, lanes 0..4 carry ushort8 (40 cols); logits = self + mean + b2.
__global__ __launch_bounds__(256) void agg2(
    const ushort_t* __restrict__ V, const ushort_t* __restrict__ esrc,
    const int* __restrict__ deg, const float* __restrict__ b2,
    float* __restrict__ logits) {
    int idx = blockIdx.x * 256 + threadIdx.x;
    int i = idx >> 3, c = idx & 7;
    if (i >= NODES || c >= 5) return;
    int dg = deg[i];
    int n = dg < CAP ? dg : CAP;
    const ushort_t* ep = esrc + (size_t)i * CAP;
    float a0[8] = {}, a1[8] = {};
    int j = 0;
    for (; j + 8 <= n; j += 8) {
        int s0 = ep[j],     s1 = ep[j + 1], s2 = ep[j + 2], s3 = ep[j + 3];
        int s4 = ep[j + 4], s5 = ep[j + 5], s6 = ep[j + 6], s7 = ep[j + 7];
        u16x8 v0 = *reinterpret_cast<const u16x8*>(V + (size_t)s0 * 80 + 40 + c * 8);
        u16x8 v1 = *reinterpret_cast<const u16x8*>(V + (size_t)s1 * 80 + 40 + c * 8);
        u16x8 v2 = *reinterpret_cast<const u16x8*>(V + (size_t)s2 * 80 + 40 + c * 8);
        u16x8 v3 = *reinterpret_cast<const u16x8*>(V + (size_t)s3 * 80 + 40 + c * 8);
        u16x8 v4 = *reinterpret_cast<const u16x8*>(V + (size_t)s4 * 80 + 40 + c * 8);
        u16x8 v5 = *reinterpret_cast<const u16x8*>(V + (size_t)s5 * 80 + 40 + c * 8);
        u16x8 v6 = *reinterpret_cast<const u16x8*>(V + (size_t)s6 * 80 + 40 + c * 8);
        u16x8 v7 = *reinterpret_cast<const u16x8*>(V + (size_t)s7 * 80 + 40 + c * 8);
#pragma unroll
        for (int k = 0; k < 8; ++k) {
            a0[k] += (bf2f(v0[k]) + bf2f(v2[k])) + (bf2f(v4[k]) + bf2f(v6[k]));
            a1[k] += (bf2f(v1[k]) + bf2f(v3[k])) + (bf2f(v5[k]) + bf2f(v7[k]));
        }
    }
    for (; j + 4 <= n; j += 4) {
        int s0 = ep[j], s1 = ep[j + 1], s2 = ep[j + 2], s3 = ep[j + 3];
        u16x8 v0 = *reinterpret_cast<const u16x8*>(V + (size_t)s0 * 80 + 40 + c * 8);
        u16x8 v1 = *reinterpret_cast<const u16x8*>(V + (size_t)s1 * 80 + 40 + c * 8);
        u16x8 v2 = *reinterpret_cast<const u16x8*>(V + (size_t)s2 * 80 + 40 + c * 8);
        u16x8 v3 = *reinterpret_cast<const u16x8*>(V + (size_t)s3 * 80 + 40 + c * 8);
#pragma unroll
        for (int k = 0; k < 8; ++k) {
            a0[k] += bf2f(v0[k]) + bf2f(v2[k]);
            a1[k] += bf2f(v1[k]) + bf2f(v3[k]);
        }
    }
    for (; j < n; ++j) {
        int s = ep[j];
        u16x8 v = *reinterpret_cast<const u16x8*>(V + (size_t)s * 80 + 40 + c * 8);
#pragma unroll
        for (int k = 0; k < 8; ++k) a0[k] += bf2f(v[k]);
    }
    float ci = 1.0f / fmaxf((float)dg, 1.0f);
    u16x8 sv = *reinterpret_cast<const u16x8*>(V + (size_t)i * 80 + c * 8);
    float o[8];
#pragma unroll
    for (int k = 0; k < 8; ++k)
        o[k] = bf2f(sv[k]) + (a0[k] + a1[k]) * ci + b2[c * 8 + k];
    float4* dst4 = reinterpret_cast<float4*>(logits + (size_t)i * 40 + c * 8);
    dst4[0] = make_float4(o[0], o[1], o[2], o[3]);
    dst4[1] = make_float4(o[4], o[5], o[6], o[7]);
}

extern "C" void kernel_launch(void* const* d_in, const int* in_sizes, int n_in,
                              void* d_out, int out_size, void* d_ws, size_t ws_size,
                              hipStream_t stream) {
    const float* x   = (const float*)d_in[0];
    const int*   ei  = (const int*)d_in[1];
    const float* Wl1 = (const float*)d_in[2];
    const float* Wr1 = (const float*)d_in[3];
    const float* b1  = (const float*)d_in[4];
    const float* Wl2 = (const float*)d_in[5];
    const float* Wr2 = (const float*)d_in[6];
    const float* b2  = (const float*)d_in[7];
    const int* src = ei;              // edge_index[0]
    const int* dst = ei + EDGES;      // edge_index[1]

    // Workspace (~40.3 MB):
    //   [0, 25.6M)       A1 [50000x256 bf16] = [xbf | mbf]
    //   [25.6M, 33.6M)   V  [50000x80 bf16]
    //   [33.6M, 40.0M)   esrc [50000*64 ushort]
    //   [40.0M, 40.2M)   deg [50000 int]
    //   [40.2M, ...)     w1p [32768 bf16 packed], w2p [10240 bf16 packed]
    char* ws = (char*)d_ws;
    ushort_t* A1   = (ushort_t*)ws;
    ushort_t* V    = (ushort_t*)(ws + 25600000);
    ushort_t* esrc = (ushort_t*)(ws + 33600000);
    int*      deg  = (int*)(ws + 40000000);
    ushort_t* w1p  = (ushort_t*)(ws + 40200000);
    ushort_t* w2p  = (ushort_t*)(ws + 40265536);

    float* logits_out = (float*)d_out;                   // 50000*40 f32
    float* emb_out    = logits_out + (size_t)NODES * 40; // 50000*128 f32

    zerok<<<98, 256, 0, stream>>>(deg);

    prep<<<9399, 256, 0, stream>>>(x, src, dst, Wr1, Wl1, Wr2, Wl2,
                                   deg, esrc, A1, w1p, w2p);

    aggx<<<3125, 256, 0, stream>>>(A1, esrc, deg);

    gemm12<<<(NODES + 63) / 64, 256, 0, stream>>>(A1, w1p, w2p, b1, emb_out, V, NODES);

    agg2<<<(NODES * 8 + 255) / 256, 256, 0, stream>>>(V, esrc, deg, b2, logits_out);
}